// Round 1
// baseline (73.689 us; speedup 1.0000x reference)
//
#include <hip/hip_runtime.h>
#include <math.h>

#define TILE 512   // ori points staged per LDS tile (10 KB LDS)

// K1: per-(ori-chunk, adv-point) partial min of squared distance.
// d(a,b) = a2 + (b2 - 2*a.b); a2 added at the end (constant per thread).
// Intensity channel (w) pre-scaled by 0.5 on both sides.
__global__ __launch_bounds__(256) void hd_partial_min(
    const float* __restrict__ adv, const float* __restrict__ ori,
    float* __restrict__ ws, float* __restrict__ out,
    int N, int M, int N_pad, int chunks)
{
    __shared__ float4 sb[TILE];
    __shared__ float  sb2[TILE];

    const int tid = threadIdx.x;
    const int i   = blockIdx.x * 256 + tid;

    // zero the output exactly once (K2 atomicMax's into it; harness poisons it)
    if (blockIdx.x == 0 && blockIdx.y == 0 && tid == 0) out[0] = 0.0f;

    float4 a = make_float4(0.f, 0.f, 0.f, 0.f);
    if (i < N) {
        a = ((const float4*)adv)[i];
        a.w *= 0.5f;
    }

    // 4 independent min accumulators -> 4x shorter v_min dependency chain
    float m0 = INFINITY, m1 = INFINITY, m2 = INFINITY, m3 = INFINITY;

    for (int base = blockIdx.y * TILE; base < M; base += chunks * TILE) {
        // stage TILE ori points: scaled coords + precomputed b2
        for (int k = tid; k < TILE; k += 256) {
            int j = base + k;
            float4 b = make_float4(0.f, 0.f, 0.f, 0.f);
            float b2 = INFINITY;               // pad entries can never win the min
            if (j < M) {
                b = ((const float4*)ori)[j];
                b.w *= 0.5f;
                b2 = b.x*b.x + b.y*b.y + b.z*b.z + b.w*b.w;
            }
            sb[k]  = b;
            sb2[k] = b2;
        }
        __syncthreads();

        // wave-uniform LDS reads (broadcast, conflict-free); 6 VALU ops/pair
        for (int j = 0; j < TILE; j += 4) {
            float4 p0 = sb[j+0], p1 = sb[j+1], p2 = sb[j+2], p3 = sb[j+3];
            float  q0 = sb2[j+0], q1 = sb2[j+1], q2 = sb2[j+2], q3 = sb2[j+3];
            float c0 = fmaf(a.x, p0.x, fmaf(a.y, p0.y, fmaf(a.z, p0.z, a.w * p0.w)));
            float c1 = fmaf(a.x, p1.x, fmaf(a.y, p1.y, fmaf(a.z, p1.z, a.w * p1.w)));
            float c2 = fmaf(a.x, p2.x, fmaf(a.y, p2.y, fmaf(a.z, p2.z, a.w * p2.w)));
            float c3 = fmaf(a.x, p3.x, fmaf(a.y, p3.y, fmaf(a.z, p3.z, a.w * p3.w)));
            m0 = fminf(m0, fmaf(-2.f, c0, q0));
            m1 = fminf(m1, fmaf(-2.f, c1, q1));
            m2 = fminf(m2, fmaf(-2.f, c2, q2));
            m3 = fminf(m3, fmaf(-2.f, c3, q3));
        }
        __syncthreads();
    }

    if (i < N) {
        float a2 = a.x*a.x + a.y*a.y + a.z*a.z + a.w*a.w;
        float d  = a2 + fminf(fminf(m0, m1), fminf(m2, m3));
        // clamp tiny negatives so float-as-uint atomicMax ordering is valid;
        // cannot change the final max (which is O(1) > 0)
        ws[(size_t)blockIdx.y * N_pad + i] = fmaxf(d, 0.0f);
    }
}

// K2: per-adv-column min across ori chunks, then global max via one
// atomicMax (as uint; all values >= 0) per block.
__global__ __launch_bounds__(256) void hd_reduce(
    const float* __restrict__ ws, float* __restrict__ out,
    int N, int N_pad, int rows)
{
    int i = blockIdx.x * 256 + threadIdx.x;
    float m = 0.0f;                      // identity for the max (all vals >= 0)
    if (i < N) {
        m = INFINITY;
        for (int r = 0; r < rows; ++r)
            m = fminf(m, ws[(size_t)r * N_pad + i]);  // coalesced across threads
    }
    // wave (64-lane) max reduce
    for (int off = 32; off >= 1; off >>= 1)
        m = fmaxf(m, __shfl_down(m, off, 64));
    __shared__ float smax[4];
    int lane = threadIdx.x & 63, wave = threadIdx.x >> 6;
    if (lane == 0) smax[wave] = m;
    __syncthreads();
    if (threadIdx.x == 0) {
        float bm = fmaxf(fmaxf(smax[0], smax[1]), fmaxf(smax[2], smax[3]));
        atomicMax((unsigned int*)out, __float_as_uint(bm));  // valid: bm >= 0
    }
}

extern "C" void kernel_launch(void* const* d_in, const int* in_sizes, int n_in,
                              void* d_out, int out_size, void* d_ws, size_t ws_size,
                              hipStream_t stream) {
    const float* adv = (const float*)d_in[0];
    const float* ori = (const float*)d_in[1];
    float* out = (float*)d_out;
    float* ws  = (float*)d_ws;

    int N = in_sizes[0] / 4;
    int M = in_sizes[1] / 4;

    int nblk_x = (N + 255) / 256;        // 32 for N=8192
    int N_pad  = nblk_x * 256;

    // ori split: 16 chunks -> 512 blocks (2/CU). Fall back if ws too small.
    int chunks = 16;
    while (chunks > 1 && (size_t)chunks * (size_t)N_pad * sizeof(float) > ws_size)
        chunks >>= 1;
    int ntiles = (M + TILE - 1) / TILE;
    if (chunks > ntiles) chunks = ntiles;
    if (chunks < 1) chunks = 1;

    hd_partial_min<<<dim3(nblk_x, chunks), 256, 0, stream>>>(
        adv, ori, ws, out, N, M, N_pad, chunks);
    hd_reduce<<<nblk_x, 256, 0, stream>>>(ws, out, N, N_pad, chunks);
}